// Round 6
// baseline (269.377 us; speedup 1.0000x reference)
//
#include <hip/hip_runtime.h>
#include <hip/hip_bf16.h>

// B=2, S=2048, D=1024, H=16, HD=64.  out = proj(attn(qkv(x))), fp32 I/O,
// bf16 MFMA internally.
//
// Pipeline:
//   1. x fp32 -> bf16 (vectorized)
//   2. Wqkv, Wproj fp32 -> bf16 TRANSPOSED ([N][K]) so GEMMs take B^T
//   3. QKV GEMM (global_load_lds staging) -> Q (pre-scaled by 0.125*log2e),
//      K, V all [B*H,S,64]; epilogue goes through LDS for coalesced stores
//   4. V transpose kernel -> V^T [B*H,64,S] (reuses x_bf workspace)
//   5. Attention: no online max (scores bounded -> exp2 safe; partials are
//      ADDITIVE). Each 32-query tile's keys split across 2 waves by chunk
//      parity; o/l partials combined in LDS (1 barrier). 1024 blocks,
//      XCD-swizzled so each XCD owns 4 whole heads (L2 locality).
//   6. proj GEMM (fp32 out)

typedef __attribute__((ext_vector_type(8))) short short8;
typedef __attribute__((ext_vector_type(4))) float float4v;

#define S_LEN 2048
#define NHEAD 16
#define HDIM  64
#define DMODEL 1024

__device__ __forceinline__ unsigned short f2bf(float f) {
    union { float f; unsigned u; } v; v.f = f;
    unsigned r = v.u + 0x7FFF + ((v.u >> 16) & 1);   // RNE
    return (unsigned short)(r >> 16);
}

__device__ __forceinline__ unsigned fbits_rn(float f) {  // bits+0x8000: RN pack
    union { float f; unsigned u; } v; v.f = f;
    return v.u + 0x8000u;
}

__device__ __forceinline__ void async16(const void* g, const void* l) {
    __builtin_amdgcn_global_load_lds(
        (const __attribute__((address_space(1))) unsigned int*)g,
        (__attribute__((address_space(3))) unsigned int*)l, 16, 0, 0);
}

// ---------------------------------------------------------------------------
__global__ void f32_to_bf16_v4(const float4* __restrict__ in,
                               ushort4* __restrict__ out, int n4) {
    int i = blockIdx.x * blockDim.x + threadIdx.x;
    if (i < n4) {
        float4 v = in[i];
        ushort4 o;
        o.x = f2bf(v.x); o.y = f2bf(v.y); o.z = f2bf(v.z); o.w = f2bf(v.w);
        out[i] = o;
    }
}

// in[K][N] fp32 -> out[N][K] bf16, 64x64 tiles
__global__ __launch_bounds__(256) void transpose_f32_bf16(
    const float* __restrict__ in, unsigned short* __restrict__ out, int K, int N) {
    __shared__ float t[64][65];
    const int kb = blockIdx.y * 64, nb = blockIdx.x * 64;
    const int tid = threadIdx.x;
    const int r0 = tid >> 4, c0 = (tid & 15) * 4;
#pragma unroll
    for (int g = 0; g < 4; g++) {
        float4 v = *(const float4*)(in + (size_t)(kb + g * 16 + r0) * N + nb + c0);
        t[g * 16 + r0][c0 + 0] = v.x; t[g * 16 + r0][c0 + 1] = v.y;
        t[g * 16 + r0][c0 + 2] = v.z; t[g * 16 + r0][c0 + 3] = v.w;
    }
    __syncthreads();
#pragma unroll
    for (int g = 0; g < 4; g++) {
        int n = g * 16 + r0;
        ushort4 o;
        o.x = f2bf(t[c0 + 0][n]); o.y = f2bf(t[c0 + 1][n]);
        o.z = f2bf(t[c0 + 2][n]); o.w = f2bf(t[c0 + 3][n]);
        *(ushort4*)(out + (size_t)(nb + n) * K + kb + c0) = o;
    }
}

// V [B*H,S,64] bf16 -> Vt [B*H,64,S] bf16, 64x64 tiles
__global__ __launch_bounds__(256) void v_transpose(
    const unsigned short* __restrict__ V, unsigned short* __restrict__ Vt) {
    __shared__ unsigned short t[64 * 68];
    const int bh = blockIdx.y;
    const int s0 = blockIdx.x * 64;
    const int tid = threadIdx.x;
    const int r = tid >> 2, c0 = (tid & 3) * 16;
    const size_t base = (size_t)bh * S_LEN * HDIM;
    union { uint4 v[2]; unsigned short u[16]; } d;
    const unsigned short* src = V + base + (size_t)(s0 + r) * HDIM + c0;
    d.v[0] = *(const uint4*)(src);
    d.v[1] = *(const uint4*)(src + 8);
#pragma unroll
    for (int j = 0; j < 16; j++) t[(c0 + j) * 68 + r] = d.u[j];
    __syncthreads();
    const unsigned short* pl = t + r * 68 + c0;
    unsigned short* po = Vt + base + (size_t)r * S_LEN + s0 + c0;
#pragma unroll
    for (int j = 0; j < 2; j++) {
        uint2 a = *(const uint2*)(pl + j * 8);
        uint2 b = *(const uint2*)(pl + j * 8 + 4);
        uint4 w; w.x = a.x; w.y = a.y; w.z = b.x; w.w = b.y;
        *(uint4*)(po + j * 8) = w;
    }
}

// ---------------------------------------------------------------------------
// GEMM: C[M,N] = A[M,K] * Bt[N,K]^T + bias, bf16 in, m97 structure.
// MODE 0: Q(scaled)/K/V -> [B*H,S,64] via LDS-coalesced epilogue.
// MODE 1: fp32 out row-major.
// ---------------------------------------------------------------------------
#define QSCALE 0.18033688f   // 0.125 * log2(e), folded into Q

template<int MODE>
__global__ __launch_bounds__(256) void gemm_bt_kernel(
    const unsigned short* __restrict__ A,
    const unsigned short* __restrict__ Bt,
    const float* __restrict__ bias,
    unsigned short* __restrict__ out_q,
    unsigned short* __restrict__ out_k,
    unsigned short* __restrict__ out_v,
    float* __restrict__ out_f,
    int M, int N, int K)
{
    __shared__ unsigned short smem[128 * 68];   // K-loop: As|Bs; epilogue: Ct
    unsigned short* As = smem;
    unsigned short* Bs = smem + 128 * 32;

    const int tid  = threadIdx.x;
    const int lane = tid & 63;
    const int wave = tid >> 6;
    const int quad = lane >> 4;
    const int l16  = lane & 15;

    const int m0 = blockIdx.y * 128;
    const int n0 = blockIdx.x * 128;
    const int wm = (wave >> 1) * 64;
    const int wn = (wave & 1) * 64;

    float4v acc[4][4];
#pragma unroll
    for (int i = 0; i < 4; i++)
#pragma unroll
        for (int j = 0; j < 4; j++) acc[i][j] = (float4v){0.f, 0.f, 0.f, 0.f};

    const int srow = lane >> 2;          // row within 16-row group
    const int scol = (lane & 3) * 8;     // k offset (shorts)

    for (int k0 = 0; k0 < K; k0 += 32) {
        __syncthreads();
#pragma unroll
        for (int it = 0; it < 2; it++) {
            const int rg = it * 64 + wave * 16;
            async16(A  + (size_t)(m0 + rg + srow) * K + k0 + scol,
                    (const char*)As + rg * 64);
            async16(Bt + (size_t)(n0 + rg + srow) * K + k0 + scol,
                    (const char*)Bs + rg * 64);
        }
        __syncthreads();

        short8 af[4], bf[4];
#pragma unroll
        for (int mt = 0; mt < 4; mt++)
            af[mt] = *(const short8*)(As + (wm + mt * 16 + l16) * 32 + quad * 8);
#pragma unroll
        for (int nt = 0; nt < 4; nt++)
            bf[nt] = *(const short8*)(Bs + (wn + nt * 16 + l16) * 32 + quad * 8);
#pragma unroll
        for (int mt = 0; mt < 4; mt++)
#pragma unroll
            for (int nt = 0; nt < 4; nt++)
                acc[mt][nt] = __builtin_amdgcn_mfma_f32_16x16x32_bf16(
                    af[mt], bf[nt], acc[mt][nt], 0, 0, 0);
    }

    if (MODE == 0) {
        // two 64-col passes; writer waves have wn == ch*64. Each 64-col block
        // is exactly one head of one of Q/K/V.
#pragma unroll
        for (int ch = 0; ch < 2; ch++) {
            __syncthreads();
            if ((wave & 1) == ch) {
#pragma unroll
                for (int nt = 0; nt < 4; nt++) {
                    const int col = n0 + ch * 64 + nt * 16 + l16;
                    const float sc = ((col >> 10) == 0) ? QSCALE : 1.0f;
                    const float bia = bias[col] * sc;
#pragma unroll
                    for (int mt = 0; mt < 4; mt++)
#pragma unroll
                        for (int r = 0; r < 4; r++)
                            smem[(wm + mt * 16 + quad * 4 + r) * 68 + nt * 16 + l16]
                                = f2bf(acc[mt][nt][r] * sc + bia);
                }
            }
            __syncthreads();
            const int cb = n0 + ch * 64;
            const int part = cb >> 10;
            const int h = (cb & 1023) >> 6;
            unsigned short* dst = (part == 0) ? out_q : (part == 1) ? out_k : out_v;
            const int row = tid >> 1, haf = tid & 1;
            const int gr = m0 + row;
            const int b = gr >> 11, s = gr & 2047;
            unsigned short* po = dst + (((size_t)(b * NHEAD + h)) * S_LEN + s) * HDIM
                                 + haf * 32;
            const unsigned short* pl = smem + row * 68 + haf * 32;
            // 32 contiguous shorts per thread: 4 x uint4, gathered as uint2
            // pairs (LDS rows are 8B- but not 16B-aligned).
#pragma unroll
            for (int j = 0; j < 4; j++) {
                uint2 a = *(const uint2*)(pl + j * 8);
                uint2 bb = *(const uint2*)(pl + j * 8 + 4);
                uint4 w; w.x = a.x; w.y = a.y; w.z = bb.x; w.w = bb.y;
                *(uint4*)(po + j * 8) = w;
            }
        }
    } else {
#pragma unroll
        for (int nt = 0; nt < 4; nt++) {
            const int col = n0 + wn + nt * 16 + l16;
            const float bia = bias[col];
#pragma unroll
            for (int mt = 0; mt < 4; mt++) {
                const int rowb = m0 + wm + mt * 16 + quad * 4;
#pragma unroll
                for (int r = 0; r < 4; r++)
                    out_f[(size_t)(rowb + r) * N + col] = acc[mt][nt][r] + bia;
            }
        }
    }
}

// ---------------------------------------------------------------------------
// Attention. 1024 blocks (1D, XCD-swizzled: 4 whole heads per XCD), 4 waves.
// Block = 2 tiles (pairI, 63-pairI) x 2 key-halves. Wave (tile,half) runs
// chunks c = half, half+2, ... of its tile (additive partials; no online max).
// Partials combined in LDS once; halves 0 do the epilogue.
// ---------------------------------------------------------------------------
__global__ __launch_bounds__(256) void attn2_kernel(
    const unsigned short* __restrict__ Q,    // [B*H, S, 64] (pre-scaled)
    const unsigned short* __restrict__ Kb,   // [B*H, S, 64]
    const unsigned short* __restrict__ Vt,   // [B*H, 64, S]
    unsigned short* __restrict__ ctx)        // [B, S, H*64]
{
    __shared__ float oc[2][2][4][4][64];   // [pair][mt][nt][reg][lane]
    __shared__ float lc[2][2][64];         // [pair][mt][lane]

    const int tid  = threadIdx.x;
    const int lane = tid & 63;
    const int wave = tid >> 6;
    const int quad = lane >> 4;
    const int l16  = lane & 15;

    const int lin = blockIdx.x;
    const int xcd = lin & 7;
    const int idx = lin >> 3;                  // 0..127
    const int bh  = xcd * 4 + (idx >> 5);      // 4 whole heads per XCD
    const int pairI = idx & 31;                // 0..31

    const int T    = (wave < 2) ? pairI : (63 - pairI);
    const int half = wave & 1;
    const int pr   = wave >> 1;                // 0: tile A, 1: tile B
    const int q0 = T * 32;
    const size_t base = (size_t)bh * S_LEN * HDIM;

    short8 qf[2][2];
#pragma unroll
    for (int mt = 0; mt < 2; mt++)
#pragma unroll
        for (int h = 0; h < 2; h++)
            qf[mt][h] = *(const short8*)(Q + base + (size_t)(q0 + mt * 16 + l16) * HDIM
                                         + h * 32 + quad * 8);

    float4v o[2][4];
#pragma unroll
    for (int mt = 0; mt < 2; mt++)
#pragma unroll
        for (int nt = 0; nt < 4; nt++) o[mt][nt] = (float4v){0.f, 0.f, 0.f, 0.f};
    float lsum[2] = {0.f, 0.f};

    const int nch = (q0 >> 6) + 1;

    for (int c = half; c < nch; c += 2) {
        const int kb0 = c * 64;
        short8 kf[4][2];
        union { ushort4 h[2]; short8 s; } vf[4][2];
#pragma unroll
        for (int kt = 0; kt < 4; kt++)
#pragma unroll
            for (int h = 0; h < 2; h++)
                kf[kt][h] = *(const short8*)(Kb + base
                    + (size_t)(kb0 + kt * 16 + l16) * HDIM + h * 32 + quad * 8);
#pragma unroll
        for (int nt = 0; nt < 4; nt++)
#pragma unroll
            for (int kk = 0; kk < 2; kk++) {
                const unsigned short* vp = Vt + base
                    + (size_t)(nt * 16 + l16) * S_LEN + kb0 + kk * 32 + quad * 4;
                vf[nt][kk].h[0] = *(const ushort4*)(vp);        // keys a=0
                vf[nt][kk].h[1] = *(const ushort4*)(vp + 16);   // keys a=1
            }

        const bool lastc = (c == nch - 1);

#pragma unroll
        for (int mt = 0; mt < 2; mt++) {
            float4v st[4];
#pragma unroll
            for (int kt = 0; kt < 4; kt++) {
                st[kt] = __builtin_amdgcn_mfma_f32_16x16x32_bf16(
                    kf[kt][0], qf[mt][0], (float4v){0.f, 0.f, 0.f, 0.f}, 0, 0, 0);
                st[kt] = __builtin_amdgcn_mfma_f32_16x16x32_bf16(
                    kf[kt][1], qf[mt][1], st[kt], 0, 0, 0);
            }
            const int qpos = q0 + mt * 16 + l16;
            float p[4][4];
#pragma unroll
            for (int kt = 0; kt < 4; kt++)
#pragma unroll
                for (int r = 0; r < 4; r++) {
                    float x = st[kt][r];
                    if (lastc) {
                        int kpos = kb0 + kt * 16 + quad * 4 + r;
                        x = (kpos <= qpos) ? x : -1e30f;
                    }
                    p[kt][r] = __builtin_amdgcn_exp2f(x);
                    lsum[mt] += p[kt][r];
                }

            // pack key pairs (2j, 2j+1) -> bf16x2 (even key in low half)
            unsigned pk[4][2];
#pragma unroll
            for (int kt = 0; kt < 4; kt++)
#pragma unroll
                for (int j = 0; j < 2; j++)
                    pk[kt][j] = __builtin_amdgcn_perm(
                        fbits_rn(p[kt][2 * j + 1]), fbits_rn(p[kt][2 * j]),
                        0x07060302);
            // in-lane C->A remap: pf[kk] dword pp = keys (kk*2+(pp>>1))*16
            //                                        + quad*4 + 2*(pp&1) ..+1
            union { unsigned u[4]; short8 s; } pf[2];
#pragma unroll
            for (int kk = 0; kk < 2; kk++)
#pragma unroll
                for (int pp = 0; pp < 4; pp++)
                    pf[kk].u[pp] = pk[kk * 2 + (pp >> 1)][pp & 1];

#pragma unroll
            for (int nt = 0; nt < 4; nt++)
#pragma unroll
                for (int kk = 0; kk < 2; kk++)
                    o[mt][nt] = __builtin_amdgcn_mfma_f32_16x16x32_bf16(
                        pf[kk].s, vf[nt][kk].s, o[mt][nt], 0, 0, 0);
        }
    }

    // combine the two key-halves of each tile
    if (half == 1) {
#pragma unroll
        for (int mt = 0; mt < 2; mt++) {
            lc[pr][mt][lane] = lsum[mt];
#pragma unroll
            for (int nt = 0; nt < 4; nt++)
#pragma unroll
                for (int r = 0; r < 4; r++)
                    oc[pr][mt][nt][r][lane] = o[mt][nt][r];
        }
    }
    __syncthreads();
    if (half == 1) return;

    const int b = bh >> 4, h = bh & 15;
#pragma unroll
    for (int mt = 0; mt < 2; mt++) {
        float l = lsum[mt] + lc[pr][mt][lane];
        l += __shfl_xor(l, 16, 64);
        l += __shfl_xor(l, 32, 64);
        const float linv = 1.f / l;
        float lr[4];
#pragma unroll
        for (int r = 0; r < 4; r++) lr[r] = __shfl(linv, quad * 4 + r, 64);
#pragma unroll
        for (int r = 0; r < 4; r++) {
            const int s = q0 + mt * 16 + quad * 4 + r;
            const size_t off = ((size_t)(b * S_LEN + s)) * DMODEL + h * HDIM;
#pragma unroll
            for (int nt = 0; nt < 4; nt++)
                ctx[off + nt * 16 + l16] =
                    f2bf((o[mt][nt][r] + oc[pr][mt][nt][r][lane]) * lr[r]);
        }
    }
}

extern "C" void kernel_launch(void* const* d_in, const int* in_sizes, int n_in,
                              void* d_out, int out_size, void* d_ws, size_t ws_size,
                              hipStream_t stream) {
    const float* x     = (const float*)d_in[0];   // [2,2048,1024]
    const float* Wqkv  = (const float*)d_in[1];   // [1024,3072]
    const float* bqkv  = (const float*)d_in[2];   // [3072]
    const float* Wproj = (const float*)d_in[3];   // [1024,1024]
    const float* bproj = (const float*)d_in[4];   // [1024]
    float* out = (float*)d_out;                   // [2,2048,1024] fp32

    const int M  = 2 * S_LEN;     // 4096
    const int N1 = 3 * DMODEL;    // 3072
    const int K  = DMODEL;        // 1024

    unsigned short* x_bf    = (unsigned short*)d_ws;                  //  8 MB
    unsigned short* wqkv_t  = x_bf   + (size_t)M * K;                 //  6 MB
    unsigned short* wproj_t = wqkv_t + (size_t)K * N1;                //  2 MB
    unsigned short* q_bf    = wproj_t + (size_t)K * DMODEL;           //  8 MB
    unsigned short* k_bf    = q_bf   + (size_t)M * DMODEL;            //  8 MB
    unsigned short* v_bf    = k_bf   + (size_t)M * DMODEL;            //  8 MB
    unsigned short* ctx_bf  = v_bf   + (size_t)M * DMODEL;            //  8 MB
    unsigned short* vt_bf   = x_bf;   // alias: x_bf dead after QKV GEMM

    {
        int n4 = (M * K) / 4;
        f32_to_bf16_v4<<<n4 / 256, 256, 0, stream>>>((const float4*)x,
                                                     (ushort4*)x_bf, n4);
    }
    {
        dim3 g(N1 / 64, K / 64);
        transpose_f32_bf16<<<g, 256, 0, stream>>>(Wqkv, wqkv_t, K, N1);
    }
    {
        dim3 g(DMODEL / 64, K / 64);
        transpose_f32_bf16<<<g, 256, 0, stream>>>(Wproj, wproj_t, K, DMODEL);
    }

    dim3 g1(N1 / 128, M / 128);   // 24 x 32
    gemm_bt_kernel<0><<<g1, 256, 0, stream>>>(x_bf, wqkv_t, bqkv,
                                              q_bf, k_bf, v_bf, nullptr,
                                              M, N1, K);

    {
        dim3 g(S_LEN / 64, 2 * NHEAD);  // 32 x 32
        v_transpose<<<g, 256, 0, stream>>>(v_bf, vt_bf);
    }

    attn2_kernel<<<1024, 256, 0, stream>>>(q_bf, k_bf, vt_bf, ctx_bf);

    dim3 g3(DMODEL / 128, M / 128);   // 8 x 32
    gemm_bt_kernel<1><<<g3, 256, 0, stream>>>(ctx_bf, wproj_t, bproj,
                                              nullptr, nullptr, nullptr, out,
                                              M, DMODEL, K);
}

// Round 7
// 232.898 us; speedup vs baseline: 1.1566x; 1.1566x over previous
//
#include <hip/hip_runtime.h>
#include <hip/hip_bf16.h>

// B=2, S=2048, D=1024, H=16, HD=64.  out = proj(attn(qkv(x))), fp32 I/O,
// bf16 MFMA internally.
//
// Key lesson (R6 post-mortem): strided per-lane fragment loads are VMEM
// line-transaction bound (64 lines/instr). Attention now uses the m97 GEMM
// anatomy: dense double-buffered global_load_lds staging of K and V^T,
// shared by all 4 waves.
//
// Layouts produced by the QKV GEMM epilogue / transpose kernel:
//   Q  [bh][s][64]      (pre-scaled by 0.125*log2e)
//   K2 [bh][2][s][32]   (hd split in halves -> 64B LDS rows, m97 read pattern)
//   V  [bh][s][64]      (intermediate)
//   Vt [bh][64][S]      with 8B key-groups XOR-swizzled by (hd&15) within
//                       each 16-group window -> conflict-free b64 LDS reads
//                       (async16 LDS image == global image, so swizzle must
//                       live in the global layout)

typedef __attribute__((ext_vector_type(8))) short short8;
typedef __attribute__((ext_vector_type(4))) float float4v;

#define S_LEN 2048
#define NHEAD 16
#define HDIM  64
#define DMODEL 1024

__device__ __forceinline__ unsigned short f2bf(float f) {
    union { float f; unsigned u; } v; v.f = f;
    unsigned r = v.u + 0x7FFF + ((v.u >> 16) & 1);   // RNE
    return (unsigned short)(r >> 16);
}

__device__ __forceinline__ unsigned fbits_rn(float f) {  // bits+0x8000: RN pack
    union { float f; unsigned u; } v; v.f = f;
    return v.u + 0x8000u;
}

__device__ __forceinline__ void async16(const void* g, const void* l) {
    __builtin_amdgcn_global_load_lds(
        (const __attribute__((address_space(1))) unsigned int*)g,
        (__attribute__((address_space(3))) unsigned int*)l, 16, 0, 0);
}

// ---------------------------------------------------------------------------
__global__ void f32_to_bf16_v4(const float4* __restrict__ in,
                               ushort4* __restrict__ out, int n4) {
    int i = blockIdx.x * blockDim.x + threadIdx.x;
    if (i < n4) {
        float4 v = in[i];
        ushort4 o;
        o.x = f2bf(v.x); o.y = f2bf(v.y); o.z = f2bf(v.z); o.w = f2bf(v.w);
        out[i] = o;
    }
}

// in[K][N] fp32 -> out[N][K] bf16, 64x64 tiles
__global__ __launch_bounds__(256) void transpose_f32_bf16(
    const float* __restrict__ in, unsigned short* __restrict__ out, int K, int N) {
    __shared__ float t[64][65];
    const int kb = blockIdx.y * 64, nb = blockIdx.x * 64;
    const int tid = threadIdx.x;
    const int r0 = tid >> 4, c0 = (tid & 15) * 4;
#pragma unroll
    for (int g = 0; g < 4; g++) {
        float4 v = *(const float4*)(in + (size_t)(kb + g * 16 + r0) * N + nb + c0);
        t[g * 16 + r0][c0 + 0] = v.x; t[g * 16 + r0][c0 + 1] = v.y;
        t[g * 16 + r0][c0 + 2] = v.z; t[g * 16 + r0][c0 + 3] = v.w;
    }
    __syncthreads();
#pragma unroll
    for (int g = 0; g < 4; g++) {
        int n = g * 16 + r0;
        ushort4 o;
        o.x = f2bf(t[c0 + 0][n]); o.y = f2bf(t[c0 + 1][n]);
        o.z = f2bf(t[c0 + 2][n]); o.w = f2bf(t[c0 + 3][n]);
        *(ushort4*)(out + (size_t)(nb + n) * K + kb + c0) = o;
    }
}

// V [bh][s][64] -> Vt [bh][64][S] with key-group swizzle g -> g ^ (hd&15)
// applied within each 16-group (128B) window.
__global__ __launch_bounds__(256) void v_transpose_sw(
    const unsigned short* __restrict__ V, unsigned short* __restrict__ Vt) {
    __shared__ unsigned short t[64 * 68];
    const int bh = blockIdx.y;
    const int s0 = blockIdx.x * 64;
    const int tid = threadIdx.x;
    const int r = tid >> 2;          // load: s-row; store: hd-row
    const int c4 = tid & 3;
    const size_t base = (size_t)bh * S_LEN * HDIM;
    union { uint4 v[2]; unsigned short u[16]; } d;
    const unsigned short* src = V + base + (size_t)(s0 + r) * HDIM + c4 * 16;
    d.v[0] = *(const uint4*)(src);
    d.v[1] = *(const uint4*)(src + 8);
#pragma unroll
    for (int j = 0; j < 16; j++) t[(c4 * 16 + j) * 68 + r] = d.u[j];  // t[hd][s]
    __syncthreads();
    const int h4 = r & 15;
    const unsigned short* pl = t + r * 68 + c4 * 16;   // hd = r, keys c4*16..
    // thread's 4 groups (local g = c4*4+i) -> slots (c4*4+i)^h4, still one
    // contiguous 32B run at base (c4*4)^(h4&12), internal order i^(h4&3)
    unsigned short* po = Vt + base + (size_t)r * S_LEN + s0
                         + (((c4 * 4) ^ (h4 & 12)) << 2);
    uint2 ug[4];
#pragma unroll
    for (int i = 0; i < 4; i++)
        ug[i ^ (h4 & 3)] = *(const uint2*)(pl + i * 4);
    uint4 w0; w0.x = ug[0].x; w0.y = ug[0].y; w0.z = ug[1].x; w0.w = ug[1].y;
    uint4 w1; w1.x = ug[2].x; w1.y = ug[2].y; w1.z = ug[3].x; w1.w = ug[3].y;
    *(uint4*)(po) = w0;
    *(uint4*)(po + 8) = w1;
}

// ---------------------------------------------------------------------------
// GEMM: C[M,N] = A[M,K] * Bt[N,K]^T + bias, bf16 in, m97 structure.
// MODE 0: Q(scaled)/V -> [bh][s][64]; K -> [bh][2][s][32] (split halves).
// MODE 1: fp32 out row-major.
// ---------------------------------------------------------------------------
#define QSCALE 0.18033688f   // 0.125 * log2(e), folded into Q

template<int MODE>
__global__ __launch_bounds__(256) void gemm_bt_kernel(
    const unsigned short* __restrict__ A,
    const unsigned short* __restrict__ Bt,
    const float* __restrict__ bias,
    unsigned short* __restrict__ out_q,
    unsigned short* __restrict__ out_k,
    unsigned short* __restrict__ out_v,
    float* __restrict__ out_f,
    int M, int N, int K)
{
    __shared__ unsigned short smem[128 * 68];   // K-loop: As|Bs; epilogue: Ct
    unsigned short* As = smem;
    unsigned short* Bs = smem + 128 * 32;

    const int tid  = threadIdx.x;
    const int lane = tid & 63;
    const int wave = tid >> 6;
    const int quad = lane >> 4;
    const int l16  = lane & 15;

    const int m0 = blockIdx.y * 128;
    const int n0 = blockIdx.x * 128;
    const int wm = (wave >> 1) * 64;
    const int wn = (wave & 1) * 64;

    float4v acc[4][4];
#pragma unroll
    for (int i = 0; i < 4; i++)
#pragma unroll
        for (int j = 0; j < 4; j++) acc[i][j] = (float4v){0.f, 0.f, 0.f, 0.f};

    const int srow = lane >> 2;          // row within 16-row group
    const int scol = (lane & 3) * 8;     // k offset (shorts)

    for (int k0 = 0; k0 < K; k0 += 32) {
        __syncthreads();
#pragma unroll
        for (int it = 0; it < 2; it++) {
            const int rg = it * 64 + wave * 16;
            async16(A  + (size_t)(m0 + rg + srow) * K + k0 + scol,
                    (const char*)As + rg * 64);
            async16(Bt + (size_t)(n0 + rg + srow) * K + k0 + scol,
                    (const char*)Bs + rg * 64);
        }
        __syncthreads();

        short8 af[4], bf[4];
#pragma unroll
        for (int mt = 0; mt < 4; mt++)
            af[mt] = *(const short8*)(As + (wm + mt * 16 + l16) * 32 + quad * 8);
#pragma unroll
        for (int nt = 0; nt < 4; nt++)
            bf[nt] = *(const short8*)(Bs + (wn + nt * 16 + l16) * 32 + quad * 8);
#pragma unroll
        for (int mt = 0; mt < 4; mt++)
#pragma unroll
            for (int nt = 0; nt < 4; nt++)
                acc[mt][nt] = __builtin_amdgcn_mfma_f32_16x16x32_bf16(
                    af[mt], bf[nt], acc[mt][nt], 0, 0, 0);
    }

    if (MODE == 0) {
        // two 64-col passes through LDS; each 64-col block = one head of Q/K/V
#pragma unroll
        for (int ch = 0; ch < 2; ch++) {
            __syncthreads();
            if ((wave & 1) == ch) {
#pragma unroll
                for (int nt = 0; nt < 4; nt++) {
                    const int col = n0 + ch * 64 + nt * 16 + l16;
                    const float sc = ((col >> 10) == 0) ? QSCALE : 1.0f;
                    const float bia = bias[col] * sc;
#pragma unroll
                    for (int mt = 0; mt < 4; mt++)
#pragma unroll
                        for (int r = 0; r < 4; r++)
                            smem[(wm + mt * 16 + quad * 4 + r) * 68 + nt * 16 + l16]
                                = f2bf(acc[mt][nt][r] * sc + bia);
                }
            }
            __syncthreads();
            const int cb = n0 + ch * 64;
            const int part = cb >> 10;
            const int h = (cb & 1023) >> 6;
            const int row = tid >> 1, haf = tid & 1;
            const int gr = m0 + row;
            const int b = gr >> 11, s = gr & 2047;
            const size_t bhI = (size_t)(b * NHEAD + h);
            unsigned short* po;
            if (part == 1) {   // K split-half planes [bh][2][S][32]
                po = out_k + ((bhI * 2 + haf) * S_LEN + s) * 32;
            } else {
                unsigned short* dst = (part == 0) ? out_q : out_v;
                po = dst + (bhI * S_LEN + s) * HDIM + haf * 32;
            }
            const unsigned short* pl = smem + row * 68 + haf * 32;
#pragma unroll
            for (int j = 0; j < 4; j++) {
                uint2 a = *(const uint2*)(pl + j * 8);
                uint2 bb = *(const uint2*)(pl + j * 8 + 4);
                uint4 w; w.x = a.x; w.y = a.y; w.z = bb.x; w.w = bb.y;
                *(uint4*)(po + j * 8) = w;
            }
        }
    } else {
#pragma unroll
        for (int nt = 0; nt < 4; nt++) {
            const int col = n0 + wn + nt * 16 + l16;
            const float bia = bias[col];
#pragma unroll
            for (int mt = 0; mt < 4; mt++) {
                const int rowb = m0 + wm + mt * 16 + quad * 4;
#pragma unroll
                for (int r = 0; r < 4; r++)
                    out_f[(size_t)(rowb + r) * N + col] = acc[mt][nt][r] + bia;
            }
        }
    }
}

// ---------------------------------------------------------------------------
// Attention, m97 anatomy. 1024 blocks = 32 bh x 32 qblocks (64 queries each),
// heavy qblocks dispatched first, bh pinned to XCD via bx&7. 4 waves x 16 q.
// Per 64-key chunk: K (8KB) + Vt (8KB) staged dense via async16, double
// buffered; fragments from LDS; no online max (additive partials).
// ---------------------------------------------------------------------------
__device__ __forceinline__ void attn_stage(
    const unsigned short* __restrict__ K2, const unsigned short* __restrict__ Vt,
    unsigned short* __restrict__ Ks, unsigned short* __restrict__ Vs,
    size_t baseK, size_t baseV, int kb0, int wave, int lane)
{
#pragma unroll
    for (int it = 0; it < 2; it++)
        async16(K2 + baseK + ((size_t)it * S_LEN + kb0 + wave * 16 + (lane >> 2)) * 32
                    + (lane & 3) * 8,
                (const char*)(Ks + (it * 64 + wave * 16) * 32));
#pragma unroll
    for (int it = 0; it < 2; it++)
        async16(Vt + baseV + (size_t)(it * 32 + wave * 8 + (lane >> 3)) * S_LEN
                    + kb0 + (lane & 7) * 8,
                (const char*)(Vs + (it * 32 + wave * 8) * 64));
}

__global__ __launch_bounds__(256) void attn3_kernel(
    const unsigned short* __restrict__ Q,    // [bh][s][64] pre-scaled
    const unsigned short* __restrict__ K2,   // [bh][2][s][32]
    const unsigned short* __restrict__ Vt,   // [bh][64][S] swizzled
    unsigned short* __restrict__ ctx)        // [B, S, H*64]
{
    __shared__ unsigned short Ks[2][128 * 32];   // [buf][(h*64+key)*32]
    __shared__ unsigned short Vs[2][64 * 64];    // [buf][hd*64 + swzgroup*4]

    const int tid  = threadIdx.x;
    const int lane = tid & 63;
    const int wave = tid >> 6;
    const int quad = lane >> 4;
    const int l16  = lane & 15;

    const int bx = blockIdx.x;
    const int bh = bx & 31;                 // bh&7 == bx&7 -> head pinned to XCD
    const int qb = 31 - (bx >> 5);          // heavy blocks first
    const int q0 = qb * 64 + wave * 16;
    const int nch = qb + 1;

    const size_t baseQ = (size_t)bh * S_LEN * HDIM;
    const size_t baseK = (size_t)bh * 2 * S_LEN * 32;
    const size_t baseV = (size_t)bh * HDIM * S_LEN;

    short8 qf[2];
#pragma unroll
    for (int h = 0; h < 2; h++)
        qf[h] = *(const short8*)(Q + baseQ + (size_t)(q0 + l16) * HDIM
                                 + h * 32 + quad * 8);

    float4v o[4];
#pragma unroll
    for (int nt = 0; nt < 4; nt++) o[nt] = (float4v){0.f, 0.f, 0.f, 0.f};
    float lsum = 0.f;

    attn_stage(K2, Vt, Ks[0], Vs[0], baseK, baseV, 0, wave, lane);

    for (int c = 0; c < nch; c++) {
        const int buf = c & 1;
        __syncthreads();                      // waits stage(c) (vmcnt drain)
        if (c + 1 < nch)
            attn_stage(K2, Vt, Ks[buf ^ 1], Vs[buf ^ 1],
                       baseK, baseV, (c + 1) * 64, wave, lane);

        const int kb0 = c * 64;
        short8 kf[4][2];
#pragma unroll
        for (int kt = 0; kt < 4; kt++)
#pragma unroll
            for (int h = 0; h < 2; h++)
                kf[kt][h] = *(const short8*)&Ks[buf][(h * 64 + kt * 16 + l16) * 32
                                                     + quad * 8];
        float4v st[4];
#pragma unroll
        for (int kt = 0; kt < 4; kt++) {
            st[kt] = __builtin_amdgcn_mfma_f32_16x16x32_bf16(
                kf[kt][0], qf[0], (float4v){0.f, 0.f, 0.f, 0.f}, 0, 0, 0);
            st[kt] = __builtin_amdgcn_mfma_f32_16x16x32_bf16(
                kf[kt][1], qf[1], st[kt], 0, 0, 0);
        }
        const bool lastc = (c == nch - 1);
        const int qpos = q0 + l16;
        float p[4][4];
#pragma unroll
        for (int kt = 0; kt < 4; kt++)
#pragma unroll
            for (int r = 0; r < 4; r++) {
                float x = st[kt][r];
                if (lastc) {
                    int kpos = kb0 + kt * 16 + quad * 4 + r;
                    x = (kpos <= qpos) ? x : -1e30f;
                }
                p[kt][r] = __builtin_amdgcn_exp2f(x);
                lsum += p[kt][r];
            }

        unsigned pk[4][2];
#pragma unroll
        for (int kt = 0; kt < 4; kt++)
#pragma unroll
            for (int j = 0; j < 2; j++)
                pk[kt][j] = __builtin_amdgcn_perm(
                    fbits_rn(p[kt][2 * j + 1]), fbits_rn(p[kt][2 * j]),
                    0x07060302);
        union { unsigned u[4]; short8 s; } pf[2];
#pragma unroll
        for (int kk = 0; kk < 2; kk++)
#pragma unroll
            for (int pp = 0; pp < 4; pp++)
                pf[kk].u[pp] = pk[kk * 2 + (pp >> 1)][pp & 1];

#pragma unroll
        for (int nt = 0; nt < 4; nt++) {
            union { ushort4 h[2]; short8 s; } vf[2];
#pragma unroll
            for (int kt = 0; kt < 4; kt++)
                vf[kt >> 1].h[kt & 1] = *(const ushort4*)&Vs[buf][
                    (nt * 16 + l16) * 64 + (((kt * 4 + quad) ^ l16) << 2)];
            o[nt] = __builtin_amdgcn_mfma_f32_16x16x32_bf16(
                pf[0].s, vf[0].s, o[nt], 0, 0, 0);
            o[nt] = __builtin_amdgcn_mfma_f32_16x16x32_bf16(
                pf[1].s, vf[1].s, o[nt], 0, 0, 0);
        }
    }

    // epilogue: finish row sums (keyed by l16), redistribute to rows, store
    float l = lsum;
    l += __shfl_xor(l, 16, 64);
    l += __shfl_xor(l, 32, 64);
    const float linv = 1.f / l;
    float lr[4];
#pragma unroll
    for (int r = 0; r < 4; r++) lr[r] = __shfl(linv, quad * 4 + r, 64);

    const int b = bh >> 4, h = bh & 15;
#pragma unroll
    for (int r = 0; r < 4; r++) {
        const int s = q0 + quad * 4 + r;
        const size_t off = ((size_t)(b * S_LEN + s)) * DMODEL + h * HDIM;
#pragma unroll
        for (int nt = 0; nt < 4; nt++)
            ctx[off + nt * 16 + l16] = f2bf(o[nt][r] * lr[r]);
    }
}

extern "C" void kernel_launch(void* const* d_in, const int* in_sizes, int n_in,
                              void* d_out, int out_size, void* d_ws, size_t ws_size,
                              hipStream_t stream) {
    const float* x     = (const float*)d_in[0];   // [2,2048,1024]
    const float* Wqkv  = (const float*)d_in[1];   // [1024,3072]
    const float* bqkv  = (const float*)d_in[2];   // [3072]
    const float* Wproj = (const float*)d_in[3];   // [1024,1024]
    const float* bproj = (const float*)d_in[4];   // [1024]
    float* out = (float*)d_out;                   // [2,2048,1024] fp32

    const int M  = 2 * S_LEN;     // 4096
    const int N1 = 3 * DMODEL;    // 3072
    const int K  = DMODEL;        // 1024

    unsigned short* x_bf    = (unsigned short*)d_ws;                  //  8 MB
    unsigned short* wqkv_t  = x_bf   + (size_t)M * K;                 //  6 MB
    unsigned short* wproj_t = wqkv_t + (size_t)K * N1;                //  2 MB
    unsigned short* q_bf    = wproj_t + (size_t)K * DMODEL;           //  8 MB
    unsigned short* k_bf    = q_bf   + (size_t)M * DMODEL;            //  8 MB
    unsigned short* v_bf    = k_bf   + (size_t)M * DMODEL;            //  8 MB
    unsigned short* ctx_bf  = v_bf   + (size_t)M * DMODEL;            //  8 MB
    unsigned short* vt_bf   = x_bf;   // alias: x_bf dead after QKV GEMM

    {
        int n4 = (M * K) / 4;
        f32_to_bf16_v4<<<n4 / 256, 256, 0, stream>>>((const float4*)x,
                                                     (ushort4*)x_bf, n4);
    }
    {
        dim3 g(N1 / 64, K / 64);
        transpose_f32_bf16<<<g, 256, 0, stream>>>(Wqkv, wqkv_t, K, N1);
    }
    {
        dim3 g(DMODEL / 64, K / 64);
        transpose_f32_bf16<<<g, 256, 0, stream>>>(Wproj, wproj_t, K, DMODEL);
    }

    dim3 g1(N1 / 128, M / 128);   // 24 x 32
    gemm_bt_kernel<0><<<g1, 256, 0, stream>>>(x_bf, wqkv_t, bqkv,
                                              q_bf, k_bf, v_bf, nullptr,
                                              M, N1, K);

    {
        dim3 g(S_LEN / 64, 2 * NHEAD);  // 32 x 32
        v_transpose_sw<<<g, 256, 0, stream>>>(v_bf, vt_bf);
    }

    attn3_kernel<<<1024, 256, 0, stream>>>(q_bf, k_bf, vt_bf, ctx_bf);

    dim3 g3(DMODEL / 128, M / 128);   // 8 x 32
    gemm_bt_kernel<1><<<g3, 256, 0, stream>>>(ctx_bf, wproj_t, bproj,
                                              nullptr, nullptr, nullptr, out,
                                              M, DMODEL, K);
}

// Round 8
// 195.614 us; speedup vs baseline: 1.3771x; 1.1906x over previous
//
#include <hip/hip_runtime.h>
#include <hip/hip_bf16.h>

// B=2, S=2048, D=1024, H=16, HD=64.  out = proj(attn(qkv(x))), fp32 I/O,
// bf16 MFMA internally.
//
// R8: QKV GEMM epilogue rebuilt (R7 had 4096 LDS-conflict-cycles/block from
// ds_write_b16 lane-pairs sharing a dword): single-pass 128x132 LDS tile,
// pair-packed ds_write_b32 (conflict-free), line-coalesced store phase.
// proj GEMM re-tiled 64x128 (512 blocks = 2/CU). Weight transposes fused.

typedef __attribute__((ext_vector_type(8))) short short8;
typedef __attribute__((ext_vector_type(4))) float float4v;

#define S_LEN 2048
#define NHEAD 16
#define HDIM  64
#define DMODEL 1024

__device__ __forceinline__ unsigned short f2bf(float f) {
    union { float f; unsigned u; } v; v.f = f;
    unsigned r = v.u + 0x7FFF + ((v.u >> 16) & 1);   // RNE
    return (unsigned short)(r >> 16);
}

__device__ __forceinline__ unsigned fbits_rn(float f) {  // bits+0x8000: RN pack
    union { float f; unsigned u; } v; v.f = f;
    return v.u + 0x8000u;
}

__device__ __forceinline__ void async16(const void* g, const void* l) {
    __builtin_amdgcn_global_load_lds(
        (const __attribute__((address_space(1))) unsigned int*)g,
        (__attribute__((address_space(3))) unsigned int*)l, 16, 0, 0);
}

// ---------------------------------------------------------------------------
__global__ void f32_to_bf16_v4(const float4* __restrict__ in,
                               ushort4* __restrict__ out, int n4) {
    int i = blockIdx.x * blockDim.x + threadIdx.x;
    if (i < n4) {
        float4 v = in[i];
        ushort4 o;
        o.x = f2bf(v.x); o.y = f2bf(v.y); o.z = f2bf(v.z); o.w = f2bf(v.w);
        out[i] = o;
    }
}

// Both weight matrices, one launch. in[K][N] fp32 -> out[N][K] bf16.
__global__ __launch_bounds__(256) void w_transpose_bf16(
    const float* __restrict__ Wqkv, const float* __restrict__ Wproj,
    unsigned short* __restrict__ outQ, unsigned short* __restrict__ outP) {
    __shared__ float t[64][65];
    const float* in; unsigned short* out; int N, bxl;
    if (blockIdx.x < 48) { in = Wqkv;  out = outQ; N = 3072; bxl = blockIdx.x; }
    else                 { in = Wproj; out = outP; N = 1024; bxl = blockIdx.x - 48; }
    const int K = 1024;
    const int kb = blockIdx.y * 64, nb = bxl * 64;
    const int tid = threadIdx.x;
    const int r0 = tid >> 4, c0 = (tid & 15) * 4;
#pragma unroll
    for (int g = 0; g < 4; g++) {
        float4 v = *(const float4*)(in + (size_t)(kb + g * 16 + r0) * N + nb + c0);
        t[g * 16 + r0][c0 + 0] = v.x; t[g * 16 + r0][c0 + 1] = v.y;
        t[g * 16 + r0][c0 + 2] = v.z; t[g * 16 + r0][c0 + 3] = v.w;
    }
    __syncthreads();
#pragma unroll
    for (int g = 0; g < 4; g++) {
        int n = g * 16 + r0;
        ushort4 o;
        o.x = f2bf(t[c0 + 0][n]); o.y = f2bf(t[c0 + 1][n]);
        o.z = f2bf(t[c0 + 2][n]); o.w = f2bf(t[c0 + 3][n]);
        *(ushort4*)(out + (size_t)(nb + n) * K + kb + c0) = o;
    }
}

// V [bh][s][64] -> Vt [bh][64][S] with key-group swizzle g -> g ^ (hd&15)
// applied within each 16-group (128B) window.
__global__ __launch_bounds__(256) void v_transpose_sw(
    const unsigned short* __restrict__ V, unsigned short* __restrict__ Vt) {
    __shared__ unsigned short t[64 * 68];
    const int bh = blockIdx.y;
    const int s0 = blockIdx.x * 64;
    const int tid = threadIdx.x;
    const int r = tid >> 2;          // load: s-row; store: hd-row
    const int c4 = tid & 3;
    const size_t base = (size_t)bh * S_LEN * HDIM;
    union { uint4 v[2]; unsigned short u[16]; } d;
    const unsigned short* src = V + base + (size_t)(s0 + r) * HDIM + c4 * 16;
    d.v[0] = *(const uint4*)(src);
    d.v[1] = *(const uint4*)(src + 8);
#pragma unroll
    for (int j = 0; j < 16; j++) t[(c4 * 16 + j) * 68 + r] = d.u[j];  // t[hd][s]
    __syncthreads();
    const int h4 = r & 15;
    const unsigned short* pl = t + r * 68 + c4 * 16;   // hd = r, keys c4*16..
    unsigned short* po = Vt + base + (size_t)r * S_LEN + s0
                         + (((c4 * 4) ^ (h4 & 12)) << 2);
    uint2 ug[4];
#pragma unroll
    for (int i = 0; i < 4; i++)
        ug[i ^ (h4 & 3)] = *(const uint2*)(pl + i * 4);
    uint4 w0; w0.x = ug[0].x; w0.y = ug[0].y; w0.z = ug[1].x; w0.w = ug[1].y;
    uint4 w1; w1.x = ug[2].x; w1.y = ug[2].y; w1.z = ug[3].x; w1.w = ug[3].y;
    *(uint4*)(po) = w0;
    *(uint4*)(po + 8) = w1;
}

// ---------------------------------------------------------------------------
// QKV GEMM: C[M,3072] = A[M,1024] * Bt[3072,1024]^T + bias.
// K-loop: m97 structure (async16 staging, BK=32).
// Epilogue: single pass -> 128x132-short LDS tile (stride 66 dwords);
// pair-packed ds_write_b32 (2 lanes same dword/data = free); store phase
// 16 threads/row -> every store instr covers 8 full 128B lines.
// Outputs: Q(scaled)/V [bh][s][64], K2 [bh][2][s][32].
// ---------------------------------------------------------------------------
#define QSCALE 0.18033688f   // 0.125 * log2(e), folded into Q

__global__ __launch_bounds__(256) void gemm_qkv_kernel(
    const unsigned short* __restrict__ A,
    const unsigned short* __restrict__ Bt,
    const float* __restrict__ bias,
    unsigned short* __restrict__ out_q,
    unsigned short* __restrict__ out_k,
    unsigned short* __restrict__ out_v,
    int M, int N, int K)
{
    __shared__ unsigned short smem[128 * 132];   // K-loop: As|Bs; epilogue tile
    unsigned short* As = smem;
    unsigned short* Bs = smem + 128 * 32;

    const int tid  = threadIdx.x;
    const int lane = tid & 63;
    const int wave = tid >> 6;
    const int quad = lane >> 4;
    const int l16  = lane & 15;

    const int m0 = blockIdx.y * 128;
    const int n0 = blockIdx.x * 128;
    const int wm = (wave >> 1) * 64;
    const int wn = (wave & 1) * 64;

    float4v acc[4][4];
#pragma unroll
    for (int i = 0; i < 4; i++)
#pragma unroll
        for (int j = 0; j < 4; j++) acc[i][j] = (float4v){0.f, 0.f, 0.f, 0.f};

    const int srow = lane >> 2;
    const int scol = (lane & 3) * 8;

    for (int k0 = 0; k0 < K; k0 += 32) {
        __syncthreads();
#pragma unroll
        for (int it = 0; it < 2; it++) {
            const int rg = it * 64 + wave * 16;
            async16(A  + (size_t)(m0 + rg + srow) * K + k0 + scol,
                    (const char*)As + rg * 64);
            async16(Bt + (size_t)(n0 + rg + srow) * K + k0 + scol,
                    (const char*)Bs + rg * 64);
        }
        __syncthreads();

        short8 af[4], bf[4];
#pragma unroll
        for (int mt = 0; mt < 4; mt++)
            af[mt] = *(const short8*)(As + (wm + mt * 16 + l16) * 32 + quad * 8);
#pragma unroll
        for (int nt = 0; nt < 4; nt++)
            bf[nt] = *(const short8*)(Bs + (wn + nt * 16 + l16) * 32 + quad * 8);
#pragma unroll
        for (int mt = 0; mt < 4; mt++)
#pragma unroll
            for (int nt = 0; nt < 4; nt++)
                acc[mt][nt] = __builtin_amdgcn_mfma_f32_16x16x32_bf16(
                    af[mt], bf[nt], acc[mt][nt], 0, 0, 0);
    }

    // ---- epilogue: write phase (pair-packed b32, conflict-free) ----
    __syncthreads();
#pragma unroll
    for (int nt = 0; nt < 4; nt++) {
        const int col = n0 + wn + nt * 16 + l16;
        const float sc = ((col >> 10) == 0) ? QSCALE : 1.0f;
        const float bia = bias[col] * sc;
        const int cold = (wn + nt * 16 + l16) >> 1;   // packed-dword column
#pragma unroll
        for (int mt = 0; mt < 4; mt++)
#pragma unroll
            for (int r = 0; r < 4; r++) {
                unsigned fb = fbits_rn(acc[mt][nt][r] * sc + bia);
                unsigned fbp = (unsigned)__shfl_xor((int)fb, 1, 64);
                // dword = colEven.bf16 | colOdd.bf16<<16 (identical in both lanes)
                unsigned pd = (l16 & 1)
                    ? __builtin_amdgcn_perm(fb, fbp, 0x07060302)
                    : __builtin_amdgcn_perm(fbp, fb, 0x07060302);
                const int rowl = wm + mt * 16 + quad * 4 + r;
                *((unsigned*)smem + rowl * 66 + cold) = pd;
            }
    }
    __syncthreads();

    // ---- store phase: 16 threads/row, 16B pieces, full-line coalesced ----
#pragma unroll
    for (int ps = 0; ps < 8; ps++) {
        const int row = ps * 16 + (tid >> 4);
        const int pc  = tid & 15;
        const int col0 = pc * 8;                 // short col within 128
        const int haf = col0 >> 6;               // which 64-col head block
        const int cb = n0 + haf * 64;
        const int part = cb >> 10;               // 0 Q, 1 K, 2 V
        const int h = (cb & 1023) >> 6;
        const int gr = m0 + row;
        const int b = gr >> 11, s = gr & 2047;
        const size_t bhI = (size_t)(b * NHEAD + h);
        const unsigned short* pl = smem + row * 132 + col0;
        uint2 a = *(const uint2*)(pl);
        uint2 bb = *(const uint2*)(pl + 4);
        uint4 w; w.x = a.x; w.y = a.y; w.z = bb.x; w.w = bb.y;
        unsigned short* po;
        if (part == 1) {
            const int plane = (col0 & 63) >> 5;  // K2 [bh][2][s][32]
            po = out_k + ((bhI * 2 + plane) * S_LEN + s) * 32 + (col0 & 31);
        } else {
            unsigned short* dst = (part == 0) ? out_q : out_v;
            po = dst + (bhI * S_LEN + s) * HDIM + (col0 & 63);
        }
        *(uint4*)po = w;
    }
}

// ---------------------------------------------------------------------------
// proj GEMM: out[M,1024] fp32 = ctx[M,1024] * Wt[1024,1024]^T + bias.
// Tile 64x128 -> 512 blocks (2/CU). Waves 2x2: wave = 32 rows x 64 cols.
// ---------------------------------------------------------------------------
__global__ __launch_bounds__(256) void gemm_proj_kernel(
    const unsigned short* __restrict__ A,
    const unsigned short* __restrict__ Bt,
    const float* __restrict__ bias,
    float* __restrict__ out_f,
    int M, int N, int K)
{
    __shared__ unsigned short smem[(64 + 128) * 32];   // As 4KB | Bs 8KB
    unsigned short* As = smem;
    unsigned short* Bs = smem + 64 * 32;

    const int tid  = threadIdx.x;
    const int lane = tid & 63;
    const int wave = tid >> 6;
    const int quad = lane >> 4;
    const int l16  = lane & 15;

    const int m0 = blockIdx.y * 64;
    const int n0 = blockIdx.x * 128;
    const int wm = (wave >> 1) * 32;
    const int wn = (wave & 1) * 64;

    float4v acc[2][4];
#pragma unroll
    for (int i = 0; i < 2; i++)
#pragma unroll
        for (int j = 0; j < 4; j++) acc[i][j] = (float4v){0.f, 0.f, 0.f, 0.f};

    const int srow = lane >> 2;
    const int scol = (lane & 3) * 8;

    for (int k0 = 0; k0 < K; k0 += 32) {
        __syncthreads();
        // A: 64 rows, one async16 per thread
        async16(A + (size_t)(m0 + wave * 16 + srow) * K + k0 + scol,
                (const char*)As + wave * 1024);
        // B: 128 rows
#pragma unroll
        for (int it = 0; it < 2; it++) {
            const int rg = it * 64 + wave * 16;
            async16(Bt + (size_t)(n0 + rg + srow) * K + k0 + scol,
                    (const char*)Bs + rg * 64);
        }
        __syncthreads();

        short8 af[2], bf[4];
#pragma unroll
        for (int mt = 0; mt < 2; mt++)
            af[mt] = *(const short8*)(As + (wm + mt * 16 + l16) * 32 + quad * 8);
#pragma unroll
        for (int nt = 0; nt < 4; nt++)
            bf[nt] = *(const short8*)(Bs + (wn + nt * 16 + l16) * 32 + quad * 8);
#pragma unroll
        for (int mt = 0; mt < 2; mt++)
#pragma unroll
            for (int nt = 0; nt < 4; nt++)
                acc[mt][nt] = __builtin_amdgcn_mfma_f32_16x16x32_bf16(
                    af[mt], bf[nt], acc[mt][nt], 0, 0, 0);
    }

#pragma unroll
    for (int nt = 0; nt < 4; nt++) {
        const int col = n0 + wn + nt * 16 + l16;
        const float bia = bias[col];
#pragma unroll
        for (int mt = 0; mt < 2; mt++) {
            const int rowb = m0 + wm + mt * 16 + quad * 4;
#pragma unroll
            for (int r = 0; r < 4; r++)
                out_f[(size_t)(rowb + r) * N + col] = acc[mt][nt][r] + bia;
        }
    }
}

// ---------------------------------------------------------------------------
// Attention (unchanged from R7). 1024 blocks = 32 bh x 32 qblocks, dense
// double-buffered async16 staging of K2 + swizzled Vt, no online max.
// ---------------------------------------------------------------------------
__device__ __forceinline__ void attn_stage(
    const unsigned short* __restrict__ K2, const unsigned short* __restrict__ Vt,
    unsigned short* __restrict__ Ks, unsigned short* __restrict__ Vs,
    size_t baseK, size_t baseV, int kb0, int wave, int lane)
{
#pragma unroll
    for (int it = 0; it < 2; it++)
        async16(K2 + baseK + ((size_t)it * S_LEN + kb0 + wave * 16 + (lane >> 2)) * 32
                    + (lane & 3) * 8,
                (const char*)(Ks + (it * 64 + wave * 16) * 32));
#pragma unroll
    for (int it = 0; it < 2; it++)
        async16(Vt + baseV + (size_t)(it * 32 + wave * 8 + (lane >> 3)) * S_LEN
                    + kb0 + (lane & 7) * 8,
                (const char*)(Vs + (it * 32 + wave * 8) * 64));
}

__global__ __launch_bounds__(256) void attn3_kernel(
    const unsigned short* __restrict__ Q,    // [bh][s][64] pre-scaled
    const unsigned short* __restrict__ K2,   // [bh][2][s][32]
    const unsigned short* __restrict__ Vt,   // [bh][64][S] swizzled
    unsigned short* __restrict__ ctx)        // [B, S, H*64]
{
    __shared__ unsigned short Ks[2][128 * 32];
    __shared__ unsigned short Vs[2][64 * 64];

    const int tid  = threadIdx.x;
    const int lane = tid & 63;
    const int wave = tid >> 6;
    const int quad = lane >> 4;
    const int l16  = lane & 15;

    const int bx = blockIdx.x;
    const int bh = bx & 31;
    const int qb = 31 - (bx >> 5);
    const int q0 = qb * 64 + wave * 16;
    const int nch = qb + 1;

    const size_t baseQ = (size_t)bh * S_LEN * HDIM;
    const size_t baseK = (size_t)bh * 2 * S_LEN * 32;
    const size_t baseV = (size_t)bh * HDIM * S_LEN;

    short8 qf[2];
#pragma unroll
    for (int h = 0; h < 2; h++)
        qf[h] = *(const short8*)(Q + baseQ + (size_t)(q0 + l16) * HDIM
                                 + h * 32 + quad * 8);

    float4v o[4];
#pragma unroll
    for (int nt = 0; nt < 4; nt++) o[nt] = (float4v){0.f, 0.f, 0.f, 0.f};
    float lsum = 0.f;

    attn_stage(K2, Vt, Ks[0], Vs[0], baseK, baseV, 0, wave, lane);

    for (int c = 0; c < nch; c++) {
        const int buf = c & 1;
        __syncthreads();
        if (c + 1 < nch)
            attn_stage(K2, Vt, Ks[buf ^ 1], Vs[buf ^ 1],
                       baseK, baseV, (c + 1) * 64, wave, lane);

        const int kb0 = c * 64;
        short8 kf[4][2];
#pragma unroll
        for (int kt = 0; kt < 4; kt++)
#pragma unroll
            for (int h = 0; h < 2; h++)
                kf[kt][h] = *(const short8*)&Ks[buf][(h * 64 + kt * 16 + l16) * 32
                                                     + quad * 8];
        float4v st[4];
#pragma unroll
        for (int kt = 0; kt < 4; kt++) {
            st[kt] = __builtin_amdgcn_mfma_f32_16x16x32_bf16(
                kf[kt][0], qf[0], (float4v){0.f, 0.f, 0.f, 0.f}, 0, 0, 0);
            st[kt] = __builtin_amdgcn_mfma_f32_16x16x32_bf16(
                kf[kt][1], qf[1], st[kt], 0, 0, 0);
        }
        const bool lastc = (c == nch - 1);
        const int qpos = q0 + l16;
        float p[4][4];
#pragma unroll
        for (int kt = 0; kt < 4; kt++)
#pragma unroll
            for (int r = 0; r < 4; r++) {
                float x = st[kt][r];
                if (lastc) {
                    int kpos = kb0 + kt * 16 + quad * 4 + r;
                    x = (kpos <= qpos) ? x : -1e30f;
                }
                p[kt][r] = __builtin_amdgcn_exp2f(x);
                lsum += p[kt][r];
            }

        unsigned pk[4][2];
#pragma unroll
        for (int kt = 0; kt < 4; kt++)
#pragma unroll
            for (int j = 0; j < 2; j++)
                pk[kt][j] = __builtin_amdgcn_perm(
                    fbits_rn(p[kt][2 * j + 1]), fbits_rn(p[kt][2 * j]),
                    0x07060302);
        union { unsigned u[4]; short8 s; } pf[2];
#pragma unroll
        for (int kk = 0; kk < 2; kk++)
#pragma unroll
            for (int pp = 0; pp < 4; pp++)
                pf[kk].u[pp] = pk[kk * 2 + (pp >> 1)][pp & 1];

#pragma unroll
        for (int nt = 0; nt < 4; nt++) {
            union { ushort4 h[2]; short8 s; } vf[2];
#pragma unroll
            for (int kt = 0; kt < 4; kt++)
                vf[kt >> 1].h[kt & 1] = *(const ushort4*)&Vs[buf][
                    (nt * 16 + l16) * 64 + (((kt * 4 + quad) ^ l16) << 2)];
            o[nt] = __builtin_amdgcn_mfma_f32_16x16x32_bf16(
                pf[0].s, vf[0].s, o[nt], 0, 0, 0);
            o[nt] = __builtin_amdgcn_mfma_f32_16x16x32_bf16(
                pf[1].s, vf[1].s, o[nt], 0, 0, 0);
        }
    }

    float l = lsum;
    l += __shfl_xor(l, 16, 64);
    l += __shfl_xor(l, 32, 64);
    const float linv = 1.f / l;
    float lr[4];
#pragma unroll
    for (int r = 0; r < 4; r++) lr[r] = __shfl(linv, quad * 4 + r, 64);

    const int b = bh >> 4, h = bh & 15;
#pragma unroll
    for (int r = 0; r < 4; r++) {
        const int s = q0 + quad * 4 + r;
        const size_t off = ((size_t)(b * S_LEN + s)) * DMODEL + h * HDIM;
#pragma unroll
        for (int nt = 0; nt < 4; nt++)
            ctx[off + nt * 16 + l16] = f2bf(o[nt][r] * lr[r]);
    }
}

extern "C" void kernel_launch(void* const* d_in, const int* in_sizes, int n_in,
                              void* d_out, int out_size, void* d_ws, size_t ws_size,
                              hipStream_t stream) {
    const float* x     = (const float*)d_in[0];
    const float* Wqkv  = (const float*)d_in[1];
    const float* bqkv  = (const float*)d_in[2];
    const float* Wproj = (const float*)d_in[3];
    const float* bproj = (const float*)d_in[4];
    float* out = (float*)d_out;

    const int M  = 2 * S_LEN;     // 4096
    const int N1 = 3 * DMODEL;    // 3072
    const int K  = DMODEL;        // 1024

    unsigned short* x_bf    = (unsigned short*)d_ws;
    unsigned short* wqkv_t  = x_bf   + (size_t)M * K;
    unsigned short* wproj_t = wqkv_t + (size_t)K * N1;
    unsigned short* q_bf    = wproj_t + (size_t)K * DMODEL;
    unsigned short* k_bf    = q_bf   + (size_t)M * DMODEL;
    unsigned short* v_bf    = k_bf   + (size_t)M * DMODEL;
    unsigned short* ctx_bf  = v_bf   + (size_t)M * DMODEL;
    unsigned short* vt_bf   = x_bf;   // alias: x_bf dead after QKV GEMM

    {
        int n4 = (M * K) / 4;
        f32_to_bf16_v4<<<n4 / 256, 256, 0, stream>>>((const float4*)x,
                                                     (ushort4*)x_bf, n4);
    }
    {
        dim3 g(64, 16);   // 48 blocks Wqkv + 16 blocks Wproj per k-slice
        w_transpose_bf16<<<g, 256, 0, stream>>>(Wqkv, Wproj, wqkv_t, wproj_t);
    }

    dim3 g1(N1 / 128, M / 128);   // 24 x 32
    gemm_qkv_kernel<<<g1, 256, 0, stream>>>(x_bf, wqkv_t, bqkv,
                                            q_bf, k_bf, v_bf, M, N1, K);

    {
        dim3 g(S_LEN / 64, 2 * NHEAD);  // 32 x 32
        v_transpose_sw<<<g, 256, 0, stream>>>(v_bf, vt_bf);
    }

    attn3_kernel<<<1024, 256, 0, stream>>>(q_bf, k_bf, vt_bf, ctx_bf);

    dim3 g3(DMODEL / 128, M / 64);   // 8 x 64
    gemm_proj_kernel<<<g3, 256, 0, stream>>>(ctx_bf, wproj_t, bproj, out,
                                             M, DMODEL, K);
}